// Round 13
// baseline (132.945 us; speedup 1.0000x reference)
//
#include <hip/hip_runtime.h>
#include <math.h>

#define T_LEN      24000
#define TS         448           // samples per slice
#define NSLICE     54            // 54*448 = 24192 >= 24000 (slice 53: 256 valid)
#define SPB        4             // slices (waves) per block
#define NBLKX      14            // 14*4 = 56 wave-slots >= 54 slices
#define W_LEN      81
#define HALF_W     40
#define NK         21
#define MAXORD     10
#define NIMG_TOTAL 1561
#define NROUNDS    25            // ceil(1561/64)
#define QCAP       128           // per-wave park queue capacity
#define FS_F       48000.0f
#define C_F        343.0f
#define FS_OVER_C  (48000.0f / 343.0f)
#define PI_F       3.14159265358979323846f
#define INV_4PI_F  0.07957747154594767f
#define LOG2_BETA  (-0.15200309344504997f)   // log2(0.9)
#define NEG_SLOPE  0.01f

// ---- compile-time table of valid image triples ----
// entry: (order << 15) | (kxi << 10) | (kyi << 5) | kzi
struct Table { unsigned int e[NROUNDS * 64]; };
constexpr Table make_table() {
    Table t{};
    int n = 0;
    for (int kx = 0; kx < NK; ++kx)
        for (int ky = 0; ky < NK; ++ky)
            for (int kz = 0; kz < NK; ++kz) {
                int ax = kx >= MAXORD ? kx - MAXORD : MAXORD - kx;
                int ay = ky >= MAXORD ? ky - MAXORD : MAXORD - ky;
                int az = kz >= MAXORD ? kz - MAXORD : MAXORD - kz;
                int order = ax + ay + az;
                if (order <= MAXORD)
                    t.e[n++] = (unsigned)((order << 15) | (kx << 10) | (ky << 5) | kz);
            }
    for (int i = n; i < NROUNDS * 64; ++i) t.e[i] = t.e[n - 1];  // pad (masked)
    return t;
}
__constant__ Table g_tbl = make_table();

// One image (uniform amp/delay broadcast from LDS): pure-register tap math.
#define PROCESS(aU, dU)                                                        \
    do {                                                                       \
        float t0b  = floorf(dU);                                              \
        float frac = (dU) - t0b;                                              \
        float sp   = __sinf(PI_F * frac);                                     \
        float pv   = sg * sp;                                                 \
        int   idx  = (int)t0b - HALF_W + lane - lo;                           \
        float x1p  = c1p - PI_F * frac;                                       \
        float sv1  = (x1p == 0.0f) ? 1.0f : pv * __builtin_amdgcn_rcpf(x1p);  \
        if ((unsigned)idx < (unsigned)nout)                                   \
            atomicAdd(&rirw[idx], (aU) * sv1 * hw1);                          \
        if (lane < 17) {                                                      \
            int idx2 = idx + 64;                                              \
            float sv2 = pv * __builtin_amdgcn_rcpf(x1p + 64.0f * PI_F);       \
            if ((unsigned)idx2 < (unsigned)nout)                              \
                atomicAdd(&rirw[idx2], (aU) * sv2 * hw2);                     \
        }                                                                      \
    } while (0)

__global__ __launch_bounds__(256)
void rir_quad_kernel(const float* __restrict__ g_in,
                     const float* __restrict__ W1, const float* __restrict__ b1,
                     const float* __restrict__ W2, const float* __restrict__ b2,
                     const float* __restrict__ W3, const float* __restrict__ b3,
                     float* __restrict__ out_rir, float* __restrict__ out_origin)
{
    // 4 independent waves per block; everything per-wave private; NO barriers.
    __shared__ __align__(16) float  rir[SPB][TS];        // 7168 B
    __shared__ __align__(16) float2 park[SPB][QCAP];     // 4096 B
    __shared__ float dsq[SPB][64];                       // 1024 B (63 used)
    __shared__ float mlp[SPB][96];                       // 1536 B

    const int tid  = threadIdx.x;
    const int lane = tid & 63;
    const int w    = tid >> 6;
    const int s    = blockIdx.x * SPB + w;     // this wave's slice
    const int b    = blockIdx.y;
    const int lo   = s * TS;
    const int nout = min(TS, T_LEN - lo);      // <=0 for the 2 idle wave-slots

    if (nout <= 0) return;                     // wave-uniform exit (s >= 54)

    float*  rirw  = rir[w];
    float2* parkw = park[w];
    float*  dsqw  = dsq[w];
    float*  sm_in = mlp[w];                    // 22
    float*  h1    = sm_in + 24;                // 30
    float*  h2    = h1 + 30;                   // 20
    float*  zb    = h2 + 20;                   // 9
    float*  rms   = zb + 9;                    // 9

    // ---- zero private slice accumulator ----
    float4* rir4 = (float4*)rirw;
    rir4[lane] = make_float4(0.f, 0.f, 0.f, 0.f);
    if (lane < TS / 4 - 64) rir4[64 + lane] = make_float4(0.f, 0.f, 0.f, 0.f);

    // ---- per-lane loop invariants ----
    const float c1p = PI_F * (float)(lane - HALF_W);
    const float hw1 = 0.5f - 0.5f * __cosf((float)lane * (2.0f * PI_F / 80.0f));
    const float hw2 = 0.5f - 0.5f * __cosf((float)(lane + 64) * (2.0f * PI_F / 80.0f));
    const float sg  = (lane & 1) ? 1.0f : -1.0f;

    // ---- MLP + geometry (per-wave private; in-wave DS ordering, no barrier) ----
    if (lane < 22) sm_in[lane] = g_in[b * 22 + lane];
    if (lane < 30) {
        float a = b1[lane];
        const float* wp = W1 + lane * 22;
        #pragma unroll
        for (int i = 0; i < 22; ++i) a += sm_in[i] * wp[i];
        h1[lane] = (a >= 0.0f) ? a : NEG_SLOPE * a;
    }
    if (lane < 20) {
        float a = b2[lane];
        const float* wp = W2 + lane * 30;
        #pragma unroll
        for (int i = 0; i < 30; ++i) a += h1[i] * wp[i];
        h2[lane] = (a >= 0.0f) ? a : NEG_SLOPE * a;
    }
    if (lane < 9) {
        float a = b3[lane];
        const float* wp = W3 + lane * 20;
        #pragma unroll
        for (int i = 0; i < 20; ++i) a += h2[i] * wp[i];
        zb[lane] = 1.0f / (1.0f + __expf(-a));
    }
    if (lane < 3) {
        float room = zb[lane] * 20.0f;
        rms[lane]     = room;
        rms[3 + lane] = zb[3 + lane] * room;   // mic
        rms[6 + lane] = zb[6 + lane] * room;   // src
    }
    if (lane == 0 && s == 0) {
        float dx = rms[3] - rms[6], dy = rms[4] - rms[7], dz = rms[5] - rms[8];
        out_origin[b] = 40.0f + FS_F * sqrtf(dx * dx + dy * dy + dz * dz) / C_F;
    }
    if (lane < 3 * NK) {
        int a  = lane / NK;
        int kk = (lane - a * NK) - MAXORD;
        float L = rms[a], src = rms[6 + a];
        float img = ((kk & 1) == 0) ? (float)kk * L + src : (float)(kk + 1) * L - src;
        float diff = img - rms[3 + a];
        dsqw[lane] = diff * diff;
    }

    // ---- enumerate -> compact into park queue -> ILP drain (counted loop) ----
    const float lof = (float)(lo - HALF_W);
    const float hif = (float)(lo + nout - 1 + HALF_W);
    const unsigned long long below = (lane == 63) ? ~0ull >> 1
                                   : (1ull << lane) - 1ull;
    int cnt = 0;

    unsigned en = g_tbl.e[lane];               // depth-1 prefetch
    for (int r = 0; r < NROUNDS; ++r) {
        const unsigned e = en;
        if (r + 1 < NROUNDS) en = g_tbl.e[(r + 1) * 64 + lane];
        const bool live = (r * 64 + lane) < NIMG_TOTAL;

        int kzi = e & 31, kyi = (e >> 5) & 31, kxi = (e >> 10) & 31, order = (int)(e >> 15);
        float d    = sqrtf(dsqw[kxi] + dsqw[NK + kyi] + dsqw[2 * NK + kzi]);
        float dly  = 40.0f + d * FS_OVER_C;
        float t0f  = floorf(dly);
        float amp  = exp2f((float)order * LOG2_BETA) * INV_4PI_F
                     * __builtin_amdgcn_rcpf(fmaxf(d, 0.001f));
        bool hit = live && (t0f >= lof) && (t0f <= hif);

        unsigned long long m = __ballot(hit);
        int pos = cnt + (int)__popcll(m & below);
        if (hit) parkw[pos] = make_float2(amp, dly);
        cnt += (int)__popcll(m);

        if (cnt >= QCAP - 64) {                // pileup slice: drain mid-loop
            int i = 0;
            for (; i + 1 < cnt; i += 2) {
                float2 p0 = parkw[i], p1 = parkw[i + 1];
                PROCESS(p0.x, p0.y);
                PROCESS(p1.x, p1.y);
            }
            if (i < cnt) { float2 p = parkw[i]; PROCESS(p.x, p.y); }
            cnt = 0;
        }
    }

    // final drain: paired iterations -> two independent chains per step (ILP)
    {
        int i = 0;
        for (; i + 1 < cnt; i += 2) {
            float2 p0 = parkw[i], p1 = parkw[i + 1];
            PROCESS(p0.x, p0.y);
            PROCESS(p1.x, p1.y);
        }
        if (i < cnt) { float2 p = parkw[i]; PROCESS(p.x, p.y); }
    }

    // ---- coalesced float4 writeback of this wave's slice ----
    const int n4 = nout / 4;                   // 112 or 64
    float4* out4 = (float4*)(out_rir + (size_t)b * T_LEN + lo);
    out4[lane] = rir4[lane];
    if (lane + 64 < n4) out4[lane + 64] = rir4[lane + 64];
}

extern "C" void kernel_launch(void* const* d_in, const int* in_sizes, int n_in,
                              void* d_out, int out_size, void* d_ws, size_t ws_size,
                              hipStream_t stream) {
    const float* g_in = (const float*)d_in[0];
    const float* W1   = (const float*)d_in[1];
    const float* b1   = (const float*)d_in[2];
    const float* W2   = (const float*)d_in[3];
    const float* b2   = (const float*)d_in[4];
    const float* W3   = (const float*)d_in[5];
    const float* b3   = (const float*)d_in[6];

    const int B = in_sizes[0] / 22;

    float* out_rir    = (float*)d_out;
    float* out_origin = out_rir + (size_t)B * T_LEN;

    dim3 grid(NBLKX, B);   // 14 x 128 = 1792 WGs = exactly 7 per CU, co-resident
    rir_quad_kernel<<<grid, 256, 0, stream>>>(
        g_in, W1, b1, W2, b2, W3, b3, out_rir, out_origin);
}